// Round 1
// baseline (3222.323 us; speedup 1.0000x reference)
//
#include <hip/hip_runtime.h>
#include <math.h>

// Problem constants (fixed by the reference setup_inputs()).
constexpr int Nn = 100000;   // nodes
constexpr int Ee = 1200000;  // edges (excluding self-loops)
constexpr int Dd = 20;       // input feature dim
constexpr int Hh = 64;       // hidden dim
constexpr int Gg = 128;      // graphs
#define EPSF 1e-5f

// ---------------------------------------------------------------- degree
__global__ void deg_kernel(const int* __restrict__ dst, float* __restrict__ deg) {
    int i = blockIdx.x * blockDim.x + threadIdx.x;
    if (i < Ee) atomicAdd(&deg[dst[i]], 1.0f);
}

__global__ void dis_kernel(float* __restrict__ deg) {
    int i = blockIdx.x * blockDim.x + threadIdx.x;
    if (i < Nn) deg[i] = rsqrtf(deg[i] + 1.0f);  // +1 = self-loop
}

// ------------------------------------------------- z = (h @ W) * dis[n]
// block = 256 threads = 4 nodes x 64 features. W (KxH) staged in LDS.
template <int K>
__global__ void mm_scale(const float* __restrict__ h, const float* __restrict__ W,
                         const float* __restrict__ dis, float* __restrict__ z) {
    __shared__ float sW[K * Hh];
    __shared__ float sh[4][K];
    int tid = threadIdx.x;
    for (int i = tid; i < K * Hh; i += 256) sW[i] = W[i];
    int base = blockIdx.x * 4;
    for (int i = tid; i < 4 * K; i += 256) {
        int r = i / K, c = i - r * K;
        int n0 = base + r;
        sh[r][c] = (n0 < Nn) ? h[(long)n0 * K + c] : 0.0f;
    }
    __syncthreads();
    int r = tid >> 6, f = tid & 63;
    int n = base + r;
    if (n < Nn) {
        float acc = 0.0f;
#pragma unroll
        for (int k = 0; k < K; ++k) acc += sh[r][k] * sW[k * Hh + f];
        z[(long)n * Hh + f] = acc * dis[n];
    }
}

// ------------------------------------------- agg[dst] += z[src] (edges)
// 16 threads per edge, each handles 4 consecutive features (float4 load).
__global__ void edge_agg(const int* __restrict__ src, const int* __restrict__ dst,
                         const float* __restrict__ z, float* __restrict__ agg) {
    long tid = (long)blockIdx.x * blockDim.x + threadIdx.x;
    if (tid >= (long)Ee * 16) return;
    int e = (int)(tid >> 4), q = (int)(tid & 15);
    int s = src[e], d = dst[e];
    const float4 v = *reinterpret_cast<const float4*>(z + (long)s * Hh + q * 4);
    float* a = agg + (long)d * Hh + q * 4;
    atomicAdd(a + 0, v.x);
    atomicAdd(a + 1, v.y);
    atomicAdd(a + 2, v.z);
    atomicAdd(a + 3, v.w);
}

// --------------- h = relu(BN( dis[n]*(agg + z) + b )) ; z term = self-loop
__global__ void post_kernel(const float* __restrict__ agg, const float* __restrict__ z,
                            const float* __restrict__ dis, const float* __restrict__ b,
                            const float* __restrict__ g, const float* __restrict__ be,
                            const float* __restrict__ rm, const float* __restrict__ rv,
                            float* __restrict__ h) {
    int i = blockIdx.x * blockDim.x + threadIdx.x;
    if (i >= Nn * Hh) return;
    int n = i >> 6, f = i & 63;
    float val = (agg[i] + z[i]) * dis[n];
    float s = g[f] * rsqrtf(rv[f] + EPSF);
    float o = (val + b[f] - rm[f]) * s + be[f];
    h[i] = fmaxf(o, 0.0f);
}

// ---------------------------------------------------------------- pooling
__device__ __forceinline__ int lower_bound_i(const int* __restrict__ a, int n, int v) {
    int lo = 0, hi = n;
    while (lo < hi) {
        int m = (lo + hi) >> 1;
        if (a[m] < v) lo = m + 1; else hi = m;
    }
    return lo;
}

// one block per graph; batch is sorted so graph g occupies [lo, hi)
__global__ void pool_kernel(const float* __restrict__ h, const int* __restrict__ batch,
                            float* __restrict__ emb) {
    int g = blockIdx.x;
    int lo = lower_bound_i(batch, Nn, g);
    int hi = lower_bound_i(batch, Nn, g + 1);
    int tid = threadIdx.x;
    int f = tid & 63, grp = tid >> 6;
    float acc = 0.0f;
    for (int n = lo + grp; n < hi; n += 4) acc += h[(long)n * Hh + f];
    __shared__ float red[256];
    red[tid] = acc;
    __syncthreads();
    if (tid < 64) {
        float t = red[tid] + red[tid + 64] + red[tid + 128] + red[tid + 192];
        emb[g * Hh + tid] = t / fmaxf((float)(hi - lo), 1.0f);
    }
}

// ---------------------------------------------------------------- heads
__global__ void heads_kernel(const float* __restrict__ emb,
                             const float* __restrict__ sw1, const float* __restrict__ sb1,
                             const float* __restrict__ sw2, const float* __restrict__ sb2,
                             const float* __restrict__ aw1, const float* __restrict__ ab1,
                             const float* __restrict__ aw2, const float* __restrict__ ab2,
                             float* __restrict__ out) {
    int g = blockIdx.x, tid = threadIdx.x;
    __shared__ float se[64], s1[32], sa[32];
    se[tid] = emb[g * 64 + tid];
    __syncthreads();
    if (tid < 32) {
        float a1 = sb1[tid], a2 = ab1[tid];
        for (int k = 0; k < 64; ++k) {
            float e = se[k];
            a1 += e * sw1[k * 32 + tid];
            a2 += e * aw1[k * 32 + tid];
        }
        s1[tid] = fmaxf(a1, 0.0f);
        sa[tid] = fmaxf(a2, 0.0f);
    }
    __syncthreads();
    if (tid == 0) {
        float acc = sb2[0];
        for (int k = 0; k < 32; ++k) acc += s1[k] * sw2[k];
        out[g] = 1.0f / (1.0f + expf(-acc));
    }
    if (tid >= 4 && tid < 8) {
        int t = tid - 4;
        float acc = ab2[t];
        for (int k = 0; k < 32; ++k) acc += sa[k] * aw2[k * 4 + t];
        out[Gg + g * 4 + t] = acc;
    }
}

extern "C" void kernel_launch(void* const* d_in, const int* in_sizes, int n_in,
                              void* d_out, int out_size, void* d_ws, size_t ws_size,
                              hipStream_t stream) {
    const float* x   = (const float*)d_in[0];
    const int*   ei  = (const int*)d_in[1];
    const int* batch = (const int*)d_in[2];
    // d_in[3] = num_graphs (compile-time constant Gg)
    const float* W1 = (const float*)d_in[4];
    const float* b1 = (const float*)d_in[5];
    const float* W2 = (const float*)d_in[6];
    const float* b2 = (const float*)d_in[7];
    const float* W3 = (const float*)d_in[8];
    const float* b3 = (const float*)d_in[9];
    const float* g1  = (const float*)d_in[10];
    const float* be1 = (const float*)d_in[11];
    const float* rm1 = (const float*)d_in[12];
    const float* rv1 = (const float*)d_in[13];
    const float* g2  = (const float*)d_in[14];
    const float* be2 = (const float*)d_in[15];
    const float* rm2 = (const float*)d_in[16];
    const float* rv2 = (const float*)d_in[17];
    const float* g3  = (const float*)d_in[18];
    const float* be3 = (const float*)d_in[19];
    const float* rm3 = (const float*)d_in[20];
    const float* rv3 = (const float*)d_in[21];
    const float* sw1 = (const float*)d_in[22];
    const float* sb1 = (const float*)d_in[23];
    const float* sw2 = (const float*)d_in[24];
    const float* sb2 = (const float*)d_in[25];
    const float* aw1 = (const float*)d_in[26];
    const float* ab1 = (const float*)d_in[27];
    const float* aw2 = (const float*)d_in[28];
    const float* ab2 = (const float*)d_in[29];
    float* out = (float*)d_out;

    char* ws = (char*)d_ws;
    const size_t NB = (size_t)Nn * Hh * sizeof(float);  // 25.6 MB
    float* dis = (float*)ws;                            // N floats (400 KB)
    float* z   = (float*)(ws + 400000);
    float* agg = (float*)(ws + 400000 + NB);
    float* h   = (float*)(ws + 400000 + 2 * NB);
    float* emb = (float*)(ws + 400000 + 3 * NB);        // G*H floats

    const int* srcp = ei;        // edge_index[0]
    const int* dstp = ei + Ee;   // edge_index[1]

    const int edgeBlocks  = (int)(((long)Ee * 16 + 255) / 256);
    const int nodeBlocksF = (Nn * Hh + 255) / 256;  // per-element over N*H
    const int mmBlocks    = (Nn + 3) / 4;

    // degree -> dis
    hipMemsetAsync(dis, 0, (size_t)Nn * sizeof(float), stream);
    deg_kernel<<<(Ee + 255) / 256, 256, 0, stream>>>(dstp, dis);
    dis_kernel<<<(Nn + 255) / 256, 256, 0, stream>>>(dis);

    // ---- layer 1 (K = D = 20)
    mm_scale<Dd><<<mmBlocks, 256, 0, stream>>>(x, W1, dis, z);
    hipMemsetAsync(agg, 0, NB, stream);
    edge_agg<<<edgeBlocks, 256, 0, stream>>>(srcp, dstp, z, agg);
    post_kernel<<<nodeBlocksF, 256, 0, stream>>>(agg, z, dis, b1, g1, be1, rm1, rv1, h);

    // ---- layer 2 (K = H = 64)
    mm_scale<Hh><<<mmBlocks, 256, 0, stream>>>(h, W2, dis, z);
    hipMemsetAsync(agg, 0, NB, stream);
    edge_agg<<<edgeBlocks, 256, 0, stream>>>(srcp, dstp, z, agg);
    post_kernel<<<nodeBlocksF, 256, 0, stream>>>(agg, z, dis, b2, g2, be2, rm2, rv2, h);

    // ---- layer 3
    mm_scale<Hh><<<mmBlocks, 256, 0, stream>>>(h, W3, dis, z);
    hipMemsetAsync(agg, 0, NB, stream);
    edge_agg<<<edgeBlocks, 256, 0, stream>>>(srcp, dstp, z, agg);
    post_kernel<<<nodeBlocksF, 256, 0, stream>>>(agg, z, dis, b3, g3, be3, rm3, rv3, h);

    // ---- pooling + heads
    pool_kernel<<<Gg, 256, 0, stream>>>(h, batch, emb);
    heads_kernel<<<Gg, 64, 0, stream>>>(emb, sw1, sb1, sw2, sb2, aw1, ab1, aw2, ab2, out);
}

// Round 2
// 531.392 us; speedup vs baseline: 6.0639x; 6.0639x over previous
//
#include <hip/hip_runtime.h>
#include <math.h>

// Problem constants (fixed by the reference setup_inputs()).
constexpr int Nn = 100000;   // nodes
constexpr int Ee = 1200000;  // edges (excluding self-loops)
constexpr int Dd = 20;       // input feature dim
constexpr int Hh = 64;       // hidden dim
constexpr int Gg = 128;      // graphs
#define EPSF 1e-5f

// ---------------------------------------------------------------- degree
__global__ void deg_kernel(const int* __restrict__ dst, int* __restrict__ degi) {
    int i = blockIdx.x * blockDim.x + threadIdx.x;
    if (i < Ee) atomicAdd(&degi[dst[i]], 1);
}

__global__ void dis_kernel(const int* __restrict__ degi, float* __restrict__ dis) {
    int i = blockIdx.x * blockDim.x + threadIdx.x;
    if (i < Nn) dis[i] = rsqrtf((float)degi[i] + 1.0f);  // +1 = self-loop
}

// -------------------------------------------------- exclusive scan (CSR row)
// scan1: 1024 elements per block (4/thread), local exclusive scan + block sum
__global__ void scan1(const int* __restrict__ degi, int* __restrict__ row,
                      int* __restrict__ bsum) {
    __shared__ int s[256];
    int tid = threadIdx.x;
    int base = blockIdx.x * 1024 + tid * 4;
    int v0 = (base + 0 < Nn) ? degi[base + 0] : 0;
    int v1 = (base + 1 < Nn) ? degi[base + 1] : 0;
    int v2 = (base + 2 < Nn) ? degi[base + 2] : 0;
    int v3 = (base + 3 < Nn) ? degi[base + 3] : 0;
    int tsum = v0 + v1 + v2 + v3;
    s[tid] = tsum;
    for (int off = 1; off < 256; off <<= 1) {
        __syncthreads();
        int t = (tid >= off) ? s[tid - off] : 0;
        __syncthreads();
        s[tid] += t;
    }
    __syncthreads();
    int excl = s[tid] - tsum;  // exclusive within block
    if (base + 0 < Nn) row[base + 0] = excl;
    if (base + 1 < Nn) row[base + 1] = excl + v0;
    if (base + 2 < Nn) row[base + 2] = excl + v0 + v1;
    if (base + 3 < Nn) row[base + 3] = excl + v0 + v1 + v2;
    if (tid == 255) bsum[blockIdx.x] = s[255];
}

// scan2: serial exclusive scan of the (98) block sums; also writes row[N]
__global__ void scan2(int* __restrict__ bsum, int* __restrict__ row, int nb) {
    if (blockIdx.x == 0 && threadIdx.x == 0) {
        int run = 0;
        for (int b = 0; b < nb; ++b) { int t = bsum[b]; bsum[b] = run; run += t; }
        row[Nn] = run;  // == Ee
    }
}

__global__ void scan3(int* __restrict__ row, const int* __restrict__ bsum) {
    int i = blockIdx.x * blockDim.x + threadIdx.x;
    if (i < Nn) row[i] += bsum[i >> 10];
}

__global__ void copy_cursor(const int* __restrict__ row, int* __restrict__ cursor) {
    int i = blockIdx.x * blockDim.x + threadIdx.x;
    if (i < Nn) cursor[i] = row[i];
}

// scatter edges into dst-grouped CSR order (src stored per slot)
__global__ void scatter_kernel(const int* __restrict__ src, const int* __restrict__ dst,
                               int* __restrict__ cursor, int* __restrict__ csr) {
    int e = blockIdx.x * blockDim.x + threadIdx.x;
    if (e < Ee) {
        int pos = atomicAdd(&cursor[dst[e]], 1);
        csr[pos] = src[e];
    }
}

// ------------------------------------------------- z = (h @ W) * dis[n]
// block = 256 threads = 4 nodes x 64 features. W (KxH) staged in LDS.
template <int K>
__global__ void mm_scale(const float* __restrict__ h, const float* __restrict__ W,
                         const float* __restrict__ dis, float* __restrict__ z) {
    __shared__ float sW[K * Hh];
    __shared__ float sh[4][K];
    int tid = threadIdx.x;
    for (int i = tid; i < K * Hh; i += 256) sW[i] = W[i];
    int base = blockIdx.x * 4;
    for (int i = tid; i < 4 * K; i += 256) {
        int r = i / K, c = i - r * K;
        int n0 = base + r;
        sh[r][c] = (n0 < Nn) ? h[(long)n0 * K + c] : 0.0f;
    }
    __syncthreads();
    int r = tid >> 6, f = tid & 63;
    int n = base + r;
    if (n < Nn) {
        float acc = 0.0f;
#pragma unroll
        for (int k = 0; k < K; ++k) acc += sh[r][k] * sW[k * Hh + f];
        z[(long)n * Hh + f] = acc * dis[n];
    }
}

// ---------- fused: agg over CSR segment + self-loop + BN + ReLU
// one wave (64 lanes) per node; lane = feature
__global__ void agg_post(const float* __restrict__ z, const float* __restrict__ dis,
                         const int* __restrict__ row, const int* __restrict__ csr,
                         const float* __restrict__ b, const float* __restrict__ g,
                         const float* __restrict__ be, const float* __restrict__ rm,
                         const float* __restrict__ rv, float* __restrict__ h) {
    int n = (int)((blockIdx.x * (long)blockDim.x + threadIdx.x) >> 6);
    int lane = threadIdx.x & 63;
    if (n >= Nn) return;
    int e0 = row[n], e1 = row[n + 1];
    float acc = z[(long)n * Hh + lane];  // self-loop term
    int e = e0;
    for (; e + 3 < e1; e += 4) {
        int s0 = csr[e], s1 = csr[e + 1], s2 = csr[e + 2], s3 = csr[e + 3];
        float a0 = z[(long)s0 * Hh + lane];
        float a1 = z[(long)s1 * Hh + lane];
        float a2 = z[(long)s2 * Hh + lane];
        float a3 = z[(long)s3 * Hh + lane];
        acc += (a0 + a1) + (a2 + a3);
    }
    for (; e < e1; ++e) acc += z[(long)csr[e] * Hh + lane];
    float val = acc * dis[n];
    float sc = g[lane] * rsqrtf(rv[lane] + EPSF);
    float o = (val + b[lane] - rm[lane]) * sc + be[lane];
    h[(long)n * Hh + lane] = fmaxf(o, 0.0f);
}

// ---------------------------------------------------------------- pooling
__device__ __forceinline__ int lower_bound_i(const int* __restrict__ a, int n, int v) {
    int lo = 0, hi = n;
    while (lo < hi) {
        int m = (lo + hi) >> 1;
        if (a[m] < v) lo = m + 1; else hi = m;
    }
    return lo;
}

__global__ void pool_kernel(const float* __restrict__ h, const int* __restrict__ batch,
                            float* __restrict__ emb) {
    int g = blockIdx.x;
    int lo = lower_bound_i(batch, Nn, g);
    int hi = lower_bound_i(batch, Nn, g + 1);
    int tid = threadIdx.x;
    int f = tid & 63, grp = tid >> 6;
    float acc = 0.0f;
    for (int n = lo + grp; n < hi; n += 4) acc += h[(long)n * Hh + f];
    __shared__ float red[256];
    red[tid] = acc;
    __syncthreads();
    if (tid < 64) {
        float t = red[tid] + red[tid + 64] + red[tid + 128] + red[tid + 192];
        emb[g * Hh + tid] = t / fmaxf((float)(hi - lo), 1.0f);
    }
}

// ---------------------------------------------------------------- heads
__global__ void heads_kernel(const float* __restrict__ emb,
                             const float* __restrict__ sw1, const float* __restrict__ sb1,
                             const float* __restrict__ sw2, const float* __restrict__ sb2,
                             const float* __restrict__ aw1, const float* __restrict__ ab1,
                             const float* __restrict__ aw2, const float* __restrict__ ab2,
                             float* __restrict__ out) {
    int g = blockIdx.x, tid = threadIdx.x;
    __shared__ float se[64], s1[32], sa[32];
    se[tid] = emb[g * 64 + tid];
    __syncthreads();
    if (tid < 32) {
        float a1 = sb1[tid], a2 = ab1[tid];
        for (int k = 0; k < 64; ++k) {
            float e = se[k];
            a1 += e * sw1[k * 32 + tid];
            a2 += e * aw1[k * 32 + tid];
        }
        s1[tid] = fmaxf(a1, 0.0f);
        sa[tid] = fmaxf(a2, 0.0f);
    }
    __syncthreads();
    if (tid == 0) {
        float acc = sb2[0];
        for (int k = 0; k < 32; ++k) acc += s1[k] * sw2[k];
        out[g] = 1.0f / (1.0f + expf(-acc));
    }
    if (tid >= 4 && tid < 8) {
        int t = tid - 4;
        float acc = ab2[t];
        for (int k = 0; k < 32; ++k) acc += sa[k] * aw2[k * 4 + t];
        out[Gg + g * 4 + t] = acc;
    }
}

extern "C" void kernel_launch(void* const* d_in, const int* in_sizes, int n_in,
                              void* d_out, int out_size, void* d_ws, size_t ws_size,
                              hipStream_t stream) {
    const float* x   = (const float*)d_in[0];
    const int*   ei  = (const int*)d_in[1];
    const int* batch = (const int*)d_in[2];
    const float* W1 = (const float*)d_in[4];
    const float* b1 = (const float*)d_in[5];
    const float* W2 = (const float*)d_in[6];
    const float* b2 = (const float*)d_in[7];
    const float* W3 = (const float*)d_in[8];
    const float* b3 = (const float*)d_in[9];
    const float* g1  = (const float*)d_in[10];
    const float* be1 = (const float*)d_in[11];
    const float* rm1 = (const float*)d_in[12];
    const float* rv1 = (const float*)d_in[13];
    const float* g2  = (const float*)d_in[14];
    const float* be2 = (const float*)d_in[15];
    const float* rm2 = (const float*)d_in[16];
    const float* rv2 = (const float*)d_in[17];
    const float* g3  = (const float*)d_in[18];
    const float* be3 = (const float*)d_in[19];
    const float* rm3 = (const float*)d_in[20];
    const float* rv3 = (const float*)d_in[21];
    const float* sw1 = (const float*)d_in[22];
    const float* sb1 = (const float*)d_in[23];
    const float* sw2 = (const float*)d_in[24];
    const float* sb2 = (const float*)d_in[25];
    const float* aw1 = (const float*)d_in[26];
    const float* ab1 = (const float*)d_in[27];
    const float* aw2 = (const float*)d_in[28];
    const float* ab2 = (const float*)d_in[29];
    float* out = (float*)d_out;

    // ---- workspace carve-up (256B-aligned chunks)
    char* ws = (char*)d_ws;
    auto align256 = [](size_t v) { return (v + 255) & ~(size_t)255; };
    size_t off = 0;
    auto take = [&](size_t bytes) { char* p = ws + off; off += align256(bytes); return p; };
    int*   degi   = (int*)  take((size_t)Nn * 4);
    float* dis    = (float*)take((size_t)Nn * 4);
    int*   row    = (int*)  take((size_t)(Nn + 1) * 4);
    int*   cursor = (int*)  take((size_t)Nn * 4);
    int*   bsum   = (int*)  take(1024 * 4);
    int*   csr    = (int*)  take((size_t)Ee * 4);
    float* z      = (float*)take((size_t)Nn * Hh * 4);
    float* h      = (float*)take((size_t)Nn * Hh * 4);
    float* emb    = (float*)take((size_t)Gg * Hh * 4);

    const int* srcp = ei;        // edge_index[0]
    const int* dstp = ei + Ee;   // edge_index[1]

    const int nScanBlocks = (Nn + 1023) / 1024;  // 98
    const int nodeBlocks  = (Nn + 255) / 256;
    const int edgeBlocks  = (Ee + 255) / 256;
    const int mmBlocks    = (Nn + 3) / 4;
    const int aggBlocks   = (Nn + 3) / 4;        // 4 waves (nodes) per block

    // ---- degree -> dis, CSR build (once; reused by all 3 layers)
    hipMemsetAsync(degi, 0, (size_t)Nn * 4, stream);
    deg_kernel<<<edgeBlocks, 256, 0, stream>>>(dstp, degi);
    dis_kernel<<<nodeBlocks, 256, 0, stream>>>(degi, dis);
    scan1<<<nScanBlocks, 256, 0, stream>>>(degi, row, bsum);
    scan2<<<1, 64, 0, stream>>>(bsum, row, nScanBlocks);
    scan3<<<nodeBlocks, 256, 0, stream>>>(row, bsum);
    copy_cursor<<<nodeBlocks, 256, 0, stream>>>(row, cursor);
    scatter_kernel<<<edgeBlocks, 256, 0, stream>>>(srcp, dstp, cursor, csr);

    // ---- layer 1 (K = D = 20)
    mm_scale<Dd><<<mmBlocks, 256, 0, stream>>>(x, W1, dis, z);
    agg_post<<<aggBlocks, 256, 0, stream>>>(z, dis, row, csr, b1, g1, be1, rm1, rv1, h);

    // ---- layer 2 (K = H = 64)
    mm_scale<Hh><<<mmBlocks, 256, 0, stream>>>(h, W2, dis, z);
    agg_post<<<aggBlocks, 256, 0, stream>>>(z, dis, row, csr, b2, g2, be2, rm2, rv2, h);

    // ---- layer 3
    mm_scale<Hh><<<mmBlocks, 256, 0, stream>>>(h, W3, dis, z);
    agg_post<<<aggBlocks, 256, 0, stream>>>(z, dis, row, csr, b3, g3, be3, rm3, rv3, h);

    // ---- pooling + heads
    pool_kernel<<<Gg, 256, 0, stream>>>(h, batch, emb);
    heads_kernel<<<Gg, 64, 0, stream>>>(emb, sw1, sb1, sw2, sb2, aw1, ab1, aw2, ab2, out);
}

// Round 3
// 346.885 us; speedup vs baseline: 9.2893x; 1.5319x over previous
//
#include <hip/hip_runtime.h>
#include <math.h>

// Problem constants (fixed by the reference setup_inputs()).
constexpr int Nn = 100000;   // nodes
constexpr int Ee = 1200000;  // edges (excluding self-loops)
constexpr int Dd = 20;       // input feature dim
constexpr int Hh = 64;       // hidden dim
constexpr int Gg = 128;      // graphs
#define EPSF 1e-5f

// Bucketed CSR build parameters
constexpr int NPB = 128;                    // nodes per bucket (dst >> 7)
constexpr int NBK = (Nn + NPB - 1) / NPB;   // 782 buckets
constexpr int CAP = 2048;                   // bucket capacity (mean 1536, +13 sigma)
constexpr int CH  = 16384;                  // edges per workgroup in pass A

// ---------------- pass A: bucket edges, WG-reserved regions (no false sharing)
__global__ void bucketA(const int* __restrict__ src, const int* __restrict__ dst,
                        int* __restrict__ gcnt, int* __restrict__ bkt) {
    __shared__ int lh[NBK];
    __shared__ int lb[NBK];
    int tid = threadIdx.x;
    int base = blockIdx.x * CH;
    int end = min(Ee, base + CH);
    for (int i = tid; i < NBK; i += 256) lh[i] = 0;
    __syncthreads();
    for (int e = base + tid; e < end; e += 256)
        atomicAdd(&lh[dst[e] >> 7], 1);
    __syncthreads();
    for (int i = tid; i < NBK; i += 256) {
        int c = lh[i];
        lb[i] = c ? atomicAdd(&gcnt[i], c) : 0;
        lh[i] = 0;
    }
    __syncthreads();
    for (int e = base + tid; e < end; e += 256) {
        int d = dst[e];
        int b = d >> 7;
        int pos = lb[b] + atomicAdd(&lh[b], 1);
        if (pos < CAP) bkt[b * CAP + pos] = src[e] | ((d & (NPB - 1)) << 20);
    }
}

// ---------------- pass B: exclusive scan of the 782 bucket counts (1 block)
__global__ void scanB(const int* __restrict__ gcnt, int* __restrict__ gbase,
                      int* __restrict__ row) {
    __shared__ int s[256];
    int tid = threadIdx.x;
    int v[4];
    int sum = 0;
    for (int j = 0; j < 4; ++j) {
        int i = tid * 4 + j;
        v[j] = (i < NBK) ? min(gcnt[i], CAP) : 0;
        sum += v[j];
    }
    s[tid] = sum;
    for (int off = 1; off < 256; off <<= 1) {
        __syncthreads();
        int t = (tid >= off) ? s[tid - off] : 0;
        __syncthreads();
        s[tid] += t;
    }
    __syncthreads();
    int excl = s[tid] - sum;
    for (int j = 0; j < 4; ++j) {
        int i = tid * 4 + j;
        if (i < NBK) { gbase[i] = excl; excl += v[j]; }
    }
    if (tid == 0) row[Nn] = Ee;
}

// ---------------- pass C: per-bucket dense CSR placement + row + dis
__global__ void bucketC(const int* __restrict__ gcnt, const int* __restrict__ gbase,
                        const int* __restrict__ bkt, int* __restrict__ row,
                        float* __restrict__ dis, int* __restrict__ csr) {
    int b = blockIdx.x, tid = threadIdx.x;
    int cnt = min(gcnt[b], CAP);
    int base = gbase[b];
    __shared__ int sval[CAP];   // 8 KB
    __shared__ int ncnt[NPB];
    __shared__ int noff[NPB];
    __shared__ int ncur[NPB];
    if (tid < NPB) { ncnt[tid] = 0; ncur[tid] = 0; }
    __syncthreads();
    for (int i = tid; i < cnt; i += 256) {
        int v = bkt[b * CAP + i];
        sval[i] = v;
        atomicAdd(&ncnt[v >> 20], 1);
    }
    __syncthreads();
    if (tid < NPB) noff[tid] = ncnt[tid];
    __syncthreads();
    for (int off = 1; off < NPB; off <<= 1) {
        int t = (tid < NPB && tid >= off) ? noff[tid - off] : 0;
        __syncthreads();
        if (tid < NPB) noff[tid] += t;
        __syncthreads();
    }
    if (tid < NPB) {
        int excl = noff[tid] - ncnt[tid];   // inclusive -> exclusive
        noff[tid] = excl;
        int node = b * NPB + tid;
        if (node < Nn) {
            row[node] = base + excl;
            dis[node] = rsqrtf((float)ncnt[tid] + 1.0f);  // +1 = self-loop
        }
    }
    __syncthreads();
    for (int i = tid; i < cnt; i += 256) {
        int v = sval[i];
        int nl = v >> 20;
        int pos = base + noff[nl] + atomicAdd(&ncur[nl], 1);
        csr[pos] = v & 0xFFFFF;
    }
}

// ---------------- z = (h @ W) * dis[n]; W column held in registers
template <int K>
__global__ void mm_reg(const float* __restrict__ hin, const float* __restrict__ W,
                       const float* __restrict__ dis, float* __restrict__ z) {
    int tid = threadIdx.x;
    int f = tid & 63, r = tid >> 6;  // 4 node rows per block-iter
    float wcol[K];
#pragma unroll
    for (int k = 0; k < K; ++k) wcol[k] = W[k * Hh + f];
    __shared__ float sh[4][K];
    for (int qd = blockIdx.x; qd * 4 < Nn; qd += gridDim.x) {
        int n0 = qd * 4;
        __syncthreads();
        for (int i = tid; i < 4 * K; i += 256) {
            int rr = i / K, c = i - rr * K;
            int n = n0 + rr;
            sh[rr][c] = (n < Nn) ? hin[(long)n * K + c] : 0.0f;
        }
        __syncthreads();
        int n = n0 + r;
        if (n < Nn) {
            float acc = 0.0f;
#pragma unroll
            for (int k = 0; k < K; ++k) acc += sh[r][k] * wcol[k];
            z[(long)n * Hh + f] = acc * dis[n];
        }
    }
}

// ---------------- fused agg(CSR) + self-loop + BN + ReLU (float4 gather)
// one wave per node; lane = (sub=lane>>4)*edge-slot, (q=lane&15)*float4-quad
__global__ void agg_post4(const float* __restrict__ z, const float* __restrict__ dis,
                          const int* __restrict__ row, const int* __restrict__ csr,
                          const float* __restrict__ b, const float* __restrict__ g,
                          const float* __restrict__ be, const float* __restrict__ rm,
                          const float* __restrict__ rv, float* __restrict__ hout) {
    int n = (int)(((long)blockIdx.x * blockDim.x + threadIdx.x) >> 6);
    if (n >= Nn) return;
    int lane = threadIdx.x & 63, sub = lane >> 4, q = lane & 15;
    const float4* z4 = (const float4*)z;
    int e0 = row[n], e1 = row[n + 1];
    float4 acc;
    if (sub == 0) acc = z4[(long)n * 16 + q];  // self-loop term
    else acc = make_float4(0.f, 0.f, 0.f, 0.f);
    for (int e = e0 + sub; e < e1; e += 4) {
        int s = csr[e];
        float4 v = z4[(long)s * 16 + q];
        acc.x += v.x; acc.y += v.y; acc.z += v.z; acc.w += v.w;
    }
    acc.x += __shfl_xor(acc.x, 16); acc.y += __shfl_xor(acc.y, 16);
    acc.z += __shfl_xor(acc.z, 16); acc.w += __shfl_xor(acc.w, 16);
    acc.x += __shfl_xor(acc.x, 32); acc.y += __shfl_xor(acc.y, 32);
    acc.z += __shfl_xor(acc.z, 32); acc.w += __shfl_xor(acc.w, 32);
    if (sub == 0) {
        float dn = dis[n];
        float4 bb  = ((const float4*)b)[q];
        float4 gg  = ((const float4*)g)[q];
        float4 rmm = ((const float4*)rm)[q];
        float4 rvv = ((const float4*)rv)[q];
        float4 bee = ((const float4*)be)[q];
        float4 o;
        o.x = fmaxf((acc.x * dn + bb.x - rmm.x) * (gg.x * rsqrtf(rvv.x + EPSF)) + bee.x, 0.f);
        o.y = fmaxf((acc.y * dn + bb.y - rmm.y) * (gg.y * rsqrtf(rvv.y + EPSF)) + bee.y, 0.f);
        o.z = fmaxf((acc.z * dn + bb.z - rmm.z) * (gg.z * rsqrtf(rvv.z + EPSF)) + bee.z, 0.f);
        o.w = fmaxf((acc.w * dn + bb.w - rmm.w) * (gg.w * rsqrtf(rvv.w + EPSF)) + bee.w, 0.f);
        ((float4*)hout)[(long)n * 16 + q] = o;
    }
}

// ---------------- fused mean-pool + both heads (one block per graph)
__device__ __forceinline__ int lower_bound_i(const int* __restrict__ a, int n, int v) {
    int lo = 0, hi = n;
    while (lo < hi) {
        int m = (lo + hi) >> 1;
        if (a[m] < v) lo = m + 1; else hi = m;
    }
    return lo;
}

__global__ void pool_heads(const float* __restrict__ h, const int* __restrict__ batch,
                           const float* __restrict__ sw1, const float* __restrict__ sb1,
                           const float* __restrict__ sw2, const float* __restrict__ sb2,
                           const float* __restrict__ aw1, const float* __restrict__ ab1,
                           const float* __restrict__ aw2, const float* __restrict__ ab2,
                           float* __restrict__ out) {
    int gph = blockIdx.x, tid = threadIdx.x;
    __shared__ int slo, shi;
    __shared__ float4 r4[256];
    __shared__ float semb[64];
    __shared__ float s1[32], sa[32];
    if (tid == 0) {
        slo = lower_bound_i(batch, Nn, gph);
        shi = lower_bound_i(batch, Nn, gph + 1);
    }
    __syncthreads();
    int lo = slo, hi = shi;
    int q = tid & 15, sub = tid >> 4;  // 16 node rows in flight
    const float4* h4 = (const float4*)h;
    float4 acc = make_float4(0.f, 0.f, 0.f, 0.f);
    for (int n = lo + sub; n < hi; n += 16) {
        float4 v = h4[(long)n * 16 + q];
        acc.x += v.x; acc.y += v.y; acc.z += v.z; acc.w += v.w;
    }
    r4[tid] = acc;
    __syncthreads();
    if (tid < 64) {
        const float* rf = (const float*)r4;
        float s = 0.f;
        for (int sb_ = 0; sb_ < 16; ++sb_) s += rf[sb_ * 64 + tid];
        semb[tid] = s / fmaxf((float)(hi - lo), 1.0f);
    }
    __syncthreads();
    if (tid < 32) {
        float a1 = sb1[tid], a2 = ab1[tid];
        for (int k = 0; k < 64; ++k) {
            float e = semb[k];
            a1 += e * sw1[k * 32 + tid];
            a2 += e * aw1[k * 32 + tid];
        }
        s1[tid] = fmaxf(a1, 0.0f);
        sa[tid] = fmaxf(a2, 0.0f);
    }
    __syncthreads();
    if (tid == 0) {
        float acc2 = sb2[0];
        for (int k = 0; k < 32; ++k) acc2 += s1[k] * sw2[k];
        out[gph] = 1.0f / (1.0f + expf(-acc2));
    }
    if (tid >= 4 && tid < 8) {
        int t = tid - 4;
        float acc2 = ab2[t];
        for (int k = 0; k < 32; ++k) acc2 += sa[k] * aw2[k * 4 + t];
        out[Gg + gph * 4 + t] = acc2;
    }
}

extern "C" void kernel_launch(void* const* d_in, const int* in_sizes, int n_in,
                              void* d_out, int out_size, void* d_ws, size_t ws_size,
                              hipStream_t stream) {
    const float* x   = (const float*)d_in[0];
    const int*   ei  = (const int*)d_in[1];
    const int* batch = (const int*)d_in[2];
    const float* W1 = (const float*)d_in[4];
    const float* b1 = (const float*)d_in[5];
    const float* W2 = (const float*)d_in[6];
    const float* b2 = (const float*)d_in[7];
    const float* W3 = (const float*)d_in[8];
    const float* b3 = (const float*)d_in[9];
    const float* g1  = (const float*)d_in[10];
    const float* be1 = (const float*)d_in[11];
    const float* rm1 = (const float*)d_in[12];
    const float* rv1 = (const float*)d_in[13];
    const float* g2  = (const float*)d_in[14];
    const float* be2 = (const float*)d_in[15];
    const float* rm2 = (const float*)d_in[16];
    const float* rv2 = (const float*)d_in[17];
    const float* g3  = (const float*)d_in[18];
    const float* be3 = (const float*)d_in[19];
    const float* rm3 = (const float*)d_in[20];
    const float* rv3 = (const float*)d_in[21];
    const float* sw1 = (const float*)d_in[22];
    const float* sb1 = (const float*)d_in[23];
    const float* sw2 = (const float*)d_in[24];
    const float* sb2 = (const float*)d_in[25];
    const float* aw1 = (const float*)d_in[26];
    const float* ab1 = (const float*)d_in[27];
    const float* aw2 = (const float*)d_in[28];
    const float* ab2 = (const float*)d_in[29];
    float* out = (float*)d_out;

    // ---- workspace carve-up (256B-aligned chunks)
    char* ws = (char*)d_ws;
    auto align256 = [](size_t v) { return (v + 255) & ~(size_t)255; };
    size_t off = 0;
    auto take = [&](size_t bytes) { char* p = ws + off; off += align256(bytes); return p; };
    int*   gcnt  = (int*)  take((size_t)NBK * 4);
    int*   gbase = (int*)  take((size_t)NBK * 4);
    float* dis   = (float*)take((size_t)Nn * 4);
    int*   row   = (int*)  take((size_t)(Nn + 1) * 4);
    int*   bkt   = (int*)  take((size_t)NBK * CAP * 4);   // 6.4 MB
    int*   csr   = (int*)  take((size_t)Ee * 4);          // 4.8 MB
    float* z     = (float*)take((size_t)Nn * Hh * 4);     // 25.6 MB
    float* h     = (float*)take((size_t)Nn * Hh * 4);     // 25.6 MB

    const int* srcp = ei;        // edge_index[0]
    const int* dstp = ei + Ee;   // edge_index[1]

    const int nWGA      = (Ee + CH - 1) / CH;       // 74
    const int aggBlocks = (Nn + 3) / 4;             // 1 wave per node, 4/block
    const int mmBlocks  = 2048;                     // grid-stride

    // ---- CSR build (bucketed; no cross-XCD false sharing)
    hipMemsetAsync(gcnt, 0, (size_t)NBK * 4, stream);
    bucketA<<<nWGA, 256, 0, stream>>>(srcp, dstp, gcnt, bkt);
    scanB<<<1, 256, 0, stream>>>(gcnt, gbase, row);
    bucketC<<<NBK, 256, 0, stream>>>(gcnt, gbase, bkt, row, dis, csr);

    // ---- layer 1 (K = D = 20)
    mm_reg<Dd><<<mmBlocks, 256, 0, stream>>>(x, W1, dis, z);
    agg_post4<<<aggBlocks, 256, 0, stream>>>(z, dis, row, csr, b1, g1, be1, rm1, rv1, h);

    // ---- layer 2 (K = H = 64)
    mm_reg<Hh><<<mmBlocks, 256, 0, stream>>>(h, W2, dis, z);
    agg_post4<<<aggBlocks, 256, 0, stream>>>(z, dis, row, csr, b2, g2, be2, rm2, rv2, h);

    // ---- layer 3
    mm_reg<Hh><<<mmBlocks, 256, 0, stream>>>(h, W3, dis, z);
    agg_post4<<<aggBlocks, 256, 0, stream>>>(z, dis, row, csr, b3, g3, be3, rm3, rv3, h);

    // ---- fused pooling + heads
    pool_heads<<<Gg, 256, 0, stream>>>(h, batch, sw1, sb1, sw2, sb2,
                                       aw1, ab1, aw2, ab2, out);
}

// Round 4
// 321.222 us; speedup vs baseline: 10.0315x; 1.0799x over previous
//
#include <hip/hip_runtime.h>
#include <math.h>

// Problem constants (fixed by the reference setup_inputs()).
constexpr int Nn = 100000;   // nodes
constexpr int Ee = 1200000;  // edges (excluding self-loops)
constexpr int Dd = 20;       // input feature dim
constexpr int Hh = 64;       // hidden dim
constexpr int Gg = 128;      // graphs
#define EPSF 1e-5f

// Bucketed CSR build parameters
constexpr int NPB = 128;                    // nodes per bucket (dst >> 7)
constexpr int NBK = (Nn + NPB - 1) / NPB;   // 782 buckets
constexpr int CAP = 2048;                   // bucket capacity (true max ~1730)
constexpr int CH  = 2048;                   // edges per workgroup in pass A
                                            // (586 WGs -> ~2.3 waves/SIMD; was 74 WGs @ 2.9% occ)

// ---------------- pass A: bucket edges, WG-reserved regions (no false sharing)
__global__ void bucketA(const int* __restrict__ src, const int* __restrict__ dst,
                        int* __restrict__ gcnt, int* __restrict__ bkt) {
    __shared__ int lh[NBK];
    __shared__ int lb[NBK];
    int tid = threadIdx.x;
    int base = blockIdx.x * CH;
    int end = min(Ee, base + CH);
    for (int i = tid; i < NBK; i += 256) lh[i] = 0;
    __syncthreads();
    for (int e = base + tid; e < end; e += 256)
        atomicAdd(&lh[dst[e] >> 7], 1);
    __syncthreads();
    for (int i = tid; i < NBK; i += 256) {
        int c = lh[i];
        lb[i] = c ? atomicAdd(&gcnt[i], c) : 0;
        lh[i] = 0;
    }
    __syncthreads();
    for (int e = base + tid; e < end; e += 256) {
        int d = dst[e];
        int b = d >> 7;
        int pos = lb[b] + atomicAdd(&lh[b], 1);
        if (pos < CAP) bkt[b * CAP + pos] = src[e] | ((d & (NPB - 1)) << 20);
    }
}

// ---------------- pass B: exclusive scan of the 782 bucket counts (1 block)
__global__ void scanB(const int* __restrict__ gcnt, int* __restrict__ gbase,
                      int* __restrict__ row) {
    __shared__ int s[256];
    int tid = threadIdx.x;
    int v[4];
    int sum = 0;
    for (int j = 0; j < 4; ++j) {
        int i = tid * 4 + j;
        v[j] = (i < NBK) ? min(gcnt[i], CAP) : 0;
        sum += v[j];
    }
    s[tid] = sum;
    for (int off = 1; off < 256; off <<= 1) {
        __syncthreads();
        int t = (tid >= off) ? s[tid - off] : 0;
        __syncthreads();
        s[tid] += t;
    }
    __syncthreads();
    int excl = s[tid] - sum;
    for (int j = 0; j < 4; ++j) {
        int i = tid * 4 + j;
        if (i < NBK) { gbase[i] = excl; excl += v[j]; }
    }
    if (tid == 0) row[Nn] = Ee;
}

// ---------------- pass C: per-bucket dense CSR placement + row + dis
__global__ void bucketC(const int* __restrict__ gcnt, const int* __restrict__ gbase,
                        const int* __restrict__ bkt, int* __restrict__ row,
                        float* __restrict__ dis, int* __restrict__ csr) {
    int b = blockIdx.x, tid = threadIdx.x;
    int cnt = min(gcnt[b], CAP);
    int base = gbase[b];
    __shared__ int sval[CAP];   // 8 KB
    __shared__ int ncnt[NPB];
    __shared__ int noff[NPB];
    __shared__ int ncur[NPB];
    if (tid < NPB) { ncnt[tid] = 0; ncur[tid] = 0; }
    __syncthreads();
    for (int i = tid; i < cnt; i += 256) {
        int v = bkt[b * CAP + i];
        sval[i] = v;
        atomicAdd(&ncnt[v >> 20], 1);
    }
    __syncthreads();
    if (tid < NPB) noff[tid] = ncnt[tid];
    __syncthreads();
    for (int off = 1; off < NPB; off <<= 1) {
        int t = (tid < NPB && tid >= off) ? noff[tid - off] : 0;
        __syncthreads();
        if (tid < NPB) noff[tid] += t;
        __syncthreads();
    }
    if (tid < NPB) {
        int excl = noff[tid] - ncnt[tid];   // inclusive -> exclusive
        noff[tid] = excl;
        int node = b * NPB + tid;
        if (node < Nn) {
            row[node] = base + excl;
            dis[node] = rsqrtf((float)ncnt[tid] + 1.0f);  // +1 = self-loop
        }
    }
    __syncthreads();
    for (int i = tid; i < cnt; i += 256) {
        int v = sval[i];
        int nl = v >> 20;
        int pos = base + noff[nl] + atomicAdd(&ncur[nl], 1);
        csr[pos] = v & 0xFFFFF;
    }
}

// ---------------- z = (h @ W) * dis[n]; W column held in registers
template <int K>
__global__ void mm_reg(const float* __restrict__ hin, const float* __restrict__ W,
                       const float* __restrict__ dis, float* __restrict__ z) {
    int tid = threadIdx.x;
    int f = tid & 63, r = tid >> 6;  // 4 node rows per block-iter
    float wcol[K];
#pragma unroll
    for (int k = 0; k < K; ++k) wcol[k] = W[k * Hh + f];
    __shared__ float sh[4][K];
    for (int qd = blockIdx.x; qd * 4 < Nn; qd += gridDim.x) {
        int n0 = qd * 4;
        __syncthreads();
        for (int i = tid; i < 4 * K; i += 256) {
            int rr = i / K, c = i - rr * K;
            int n = n0 + rr;
            sh[rr][c] = (n < Nn) ? hin[(long)n * K + c] : 0.0f;
        }
        __syncthreads();
        int n = n0 + r;
        if (n < Nn) {
            float acc = 0.0f;
#pragma unroll
            for (int k = 0; k < K; ++k) acc += sh[r][k] * wcol[k];
            z[(long)n * Hh + f] = acc * dis[n];
        }
    }
}

// ---------------- fused agg(CSR) + self-loop + BN + ReLU (float4 gather)
// one wave per node; lane = (sub=lane>>4)*edge-slot, (q=lane&15)*float4-quad
__global__ void agg_post4(const float* __restrict__ z, const float* __restrict__ dis,
                          const int* __restrict__ row, const int* __restrict__ csr,
                          const float* __restrict__ b, const float* __restrict__ g,
                          const float* __restrict__ be, const float* __restrict__ rm,
                          const float* __restrict__ rv, float* __restrict__ hout) {
    int n = (int)(((long)blockIdx.x * blockDim.x + threadIdx.x) >> 6);
    if (n >= Nn) return;
    int lane = threadIdx.x & 63, sub = lane >> 4, q = lane & 15;
    const float4* z4 = (const float4*)z;
    int e0 = row[n], e1 = row[n + 1];
    float4 acc;
    if (sub == 0) acc = z4[(long)n * 16 + q];  // self-loop term
    else acc = make_float4(0.f, 0.f, 0.f, 0.f);
    for (int e = e0 + sub; e < e1; e += 4) {
        int s = csr[e];
        float4 v = z4[(long)s * 16 + q];
        acc.x += v.x; acc.y += v.y; acc.z += v.z; acc.w += v.w;
    }
    acc.x += __shfl_xor(acc.x, 16); acc.y += __shfl_xor(acc.y, 16);
    acc.z += __shfl_xor(acc.z, 16); acc.w += __shfl_xor(acc.w, 16);
    acc.x += __shfl_xor(acc.x, 32); acc.y += __shfl_xor(acc.y, 32);
    acc.z += __shfl_xor(acc.z, 32); acc.w += __shfl_xor(acc.w, 32);
    if (sub == 0) {
        float dn = dis[n];
        float4 bb  = ((const float4*)b)[q];
        float4 gg  = ((const float4*)g)[q];
        float4 rmm = ((const float4*)rm)[q];
        float4 rvv = ((const float4*)rv)[q];
        float4 bee = ((const float4*)be)[q];
        float4 o;
        o.x = fmaxf((acc.x * dn + bb.x - rmm.x) * (gg.x * rsqrtf(rvv.x + EPSF)) + bee.x, 0.f);
        o.y = fmaxf((acc.y * dn + bb.y - rmm.y) * (gg.y * rsqrtf(rvv.y + EPSF)) + bee.y, 0.f);
        o.z = fmaxf((acc.z * dn + bb.z - rmm.z) * (gg.z * rsqrtf(rvv.z + EPSF)) + bee.z, 0.f);
        o.w = fmaxf((acc.w * dn + bb.w - rmm.w) * (gg.w * rsqrtf(rvv.w + EPSF)) + bee.w, 0.f);
        ((float4*)hout)[(long)n * 16 + q] = o;
    }
}

// ---------------- fused mean-pool + both heads (one block per graph)
__device__ __forceinline__ int lower_bound_i(const int* __restrict__ a, int n, int v) {
    int lo = 0, hi = n;
    while (lo < hi) {
        int m = (lo + hi) >> 1;
        if (a[m] < v) lo = m + 1; else hi = m;
    }
    return lo;
}

__global__ void pool_heads(const float* __restrict__ h, const int* __restrict__ batch,
                           const float* __restrict__ sw1, const float* __restrict__ sb1,
                           const float* __restrict__ sw2, const float* __restrict__ sb2,
                           const float* __restrict__ aw1, const float* __restrict__ ab1,
                           const float* __restrict__ aw2, const float* __restrict__ ab2,
                           float* __restrict__ out) {
    int gph = blockIdx.x, tid = threadIdx.x;
    __shared__ int slo, shi;
    __shared__ float4 r4[256];
    __shared__ float semb[64];
    __shared__ float s1[32], sa[32];
    if (tid == 0) {
        slo = lower_bound_i(batch, Nn, gph);
        shi = lower_bound_i(batch, Nn, gph + 1);
    }
    __syncthreads();
    int lo = slo, hi = shi;
    int q = tid & 15, sub = tid >> 4;  // 16 node rows in flight
    const float4* h4 = (const float4*)h;
    float4 acc = make_float4(0.f, 0.f, 0.f, 0.f);
    for (int n = lo + sub; n < hi; n += 16) {
        float4 v = h4[(long)n * 16 + q];
        acc.x += v.x; acc.y += v.y; acc.z += v.z; acc.w += v.w;
    }
    r4[tid] = acc;
    __syncthreads();
    if (tid < 64) {
        const float* rf = (const float*)r4;
        float s = 0.f;
        for (int sb_ = 0; sb_ < 16; ++sb_) s += rf[sb_ * 64 + tid];
        semb[tid] = s / fmaxf((float)(hi - lo), 1.0f);
    }
    __syncthreads();
    if (tid < 32) {
        float a1 = sb1[tid], a2 = ab1[tid];
        for (int k = 0; k < 64; ++k) {
            float e = semb[k];
            a1 += e * sw1[k * 32 + tid];
            a2 += e * aw1[k * 32 + tid];
        }
        s1[tid] = fmaxf(a1, 0.0f);
        sa[tid] = fmaxf(a2, 0.0f);
    }
    __syncthreads();
    if (tid == 0) {
        float acc2 = sb2[0];
        for (int k = 0; k < 32; ++k) acc2 += s1[k] * sw2[k];
        out[gph] = 1.0f / (1.0f + expf(-acc2));
    }
    if (tid >= 4 && tid < 8) {
        int t = tid - 4;
        float acc2 = ab2[t];
        for (int k = 0; k < 32; ++k) acc2 += sa[k] * aw2[k * 4 + t];
        out[Gg + gph * 4 + t] = acc2;
    }
}

extern "C" void kernel_launch(void* const* d_in, const int* in_sizes, int n_in,
                              void* d_out, int out_size, void* d_ws, size_t ws_size,
                              hipStream_t stream) {
    const float* x   = (const float*)d_in[0];
    const int*   ei  = (const int*)d_in[1];
    const int* batch = (const int*)d_in[2];
    const float* W1 = (const float*)d_in[4];
    const float* b1 = (const float*)d_in[5];
    const float* W2 = (const float*)d_in[6];
    const float* b2 = (const float*)d_in[7];
    const float* W3 = (const float*)d_in[8];
    const float* b3 = (const float*)d_in[9];
    const float* g1  = (const float*)d_in[10];
    const float* be1 = (const float*)d_in[11];
    const float* rm1 = (const float*)d_in[12];
    const float* rv1 = (const float*)d_in[13];
    const float* g2  = (const float*)d_in[14];
    const float* be2 = (const float*)d_in[15];
    const float* rm2 = (const float*)d_in[16];
    const float* rv2 = (const float*)d_in[17];
    const float* g3  = (const float*)d_in[18];
    const float* be3 = (const float*)d_in[19];
    const float* rm3 = (const float*)d_in[20];
    const float* rv3 = (const float*)d_in[21];
    const float* sw1 = (const float*)d_in[22];
    const float* sb1 = (const float*)d_in[23];
    const float* sw2 = (const float*)d_in[24];
    const float* sb2 = (const float*)d_in[25];
    const float* aw1 = (const float*)d_in[26];
    const float* ab1 = (const float*)d_in[27];
    const float* aw2 = (const float*)d_in[28];
    const float* ab2 = (const float*)d_in[29];
    float* out = (float*)d_out;

    // ---- workspace carve-up (256B-aligned chunks)
    char* ws = (char*)d_ws;
    auto align256 = [](size_t v) { return (v + 255) & ~(size_t)255; };
    size_t off = 0;
    auto take = [&](size_t bytes) { char* p = ws + off; off += align256(bytes); return p; };
    int*   gcnt  = (int*)  take((size_t)NBK * 4);
    int*   gbase = (int*)  take((size_t)NBK * 4);
    float* dis   = (float*)take((size_t)Nn * 4);
    int*   row   = (int*)  take((size_t)(Nn + 1) * 4);
    int*   bkt   = (int*)  take((size_t)NBK * CAP * 4);   // 6.4 MB
    int*   csr   = (int*)  take((size_t)Ee * 4);          // 4.8 MB
    float* z     = (float*)take((size_t)Nn * Hh * 4);     // 25.6 MB
    float* h     = (float*)take((size_t)Nn * Hh * 4);     // 25.6 MB

    const int* srcp = ei;        // edge_index[0]
    const int* dstp = ei + Ee;   // edge_index[1]

    const int nWGA      = (Ee + CH - 1) / CH;       // 586
    const int aggBlocks = (Nn + 3) / 4;             // 1 wave per node, 4/block
    const int mmBlocks  = 2048;                     // grid-stride

    // ---- CSR build (bucketed; no cross-XCD false sharing)
    hipMemsetAsync(gcnt, 0, (size_t)NBK * 4, stream);
    bucketA<<<nWGA, 256, 0, stream>>>(srcp, dstp, gcnt, bkt);
    scanB<<<1, 256, 0, stream>>>(gcnt, gbase, row);
    bucketC<<<NBK, 256, 0, stream>>>(gcnt, gbase, bkt, row, dis, csr);

    // ---- layer 1 (K = D = 20)
    mm_reg<Dd><<<mmBlocks, 256, 0, stream>>>(x, W1, dis, z);
    agg_post4<<<aggBlocks, 256, 0, stream>>>(z, dis, row, csr, b1, g1, be1, rm1, rv1, h);

    // ---- layer 2 (K = H = 64)
    mm_reg<Hh><<<mmBlocks, 256, 0, stream>>>(h, W2, dis, z);
    agg_post4<<<aggBlocks, 256, 0, stream>>>(z, dis, row, csr, b2, g2, be2, rm2, rv2, h);

    // ---- layer 3
    mm_reg<Hh><<<mmBlocks, 256, 0, stream>>>(h, W3, dis, z);
    agg_post4<<<aggBlocks, 256, 0, stream>>>(z, dis, row, csr, b3, g3, be3, rm3, rv3, h);

    // ---- fused pooling + heads
    pool_heads<<<Gg, 256, 0, stream>>>(h, batch, sw1, sb1, sw2, sb2,
                                       aw1, ab1, aw2, ab2, out);
}

// Round 5
// 303.948 us; speedup vs baseline: 10.6016x; 1.0568x over previous
//
#include <hip/hip_runtime.h>
#include <hip/hip_fp16.h>
#include <math.h>

// Problem constants (fixed by the reference setup_inputs()).
constexpr int Nn = 100000;   // nodes
constexpr int Ee = 1200000;  // edges (excluding self-loops)
constexpr int Dd = 20;       // input feature dim
constexpr int Hh = 64;       // hidden dim
constexpr int Gg = 128;      // graphs
#define EPSF 1e-5f

// Bucketed CSR build parameters
constexpr int NPB = 128;                    // nodes per bucket (dst >> 7)
constexpr int NBK = (Nn + NPB - 1) / NPB;   // 782 buckets
constexpr int CAP = 2048;                   // bucket capacity (true max ~1730)
constexpr int CH  = 2048;                   // edges per workgroup in pass A

// ---------------- pass A: bucket edges, WG-reserved regions (no false sharing)
__global__ void bucketA(const int* __restrict__ src, const int* __restrict__ dst,
                        int* __restrict__ gcnt, int* __restrict__ bkt) {
    __shared__ int lh[NBK];
    __shared__ int lb[NBK];
    int tid = threadIdx.x;
    int base = blockIdx.x * CH;
    int end = min(Ee, base + CH);
    for (int i = tid; i < NBK; i += 256) lh[i] = 0;
    __syncthreads();
    for (int e = base + tid; e < end; e += 256)
        atomicAdd(&lh[dst[e] >> 7], 1);
    __syncthreads();
    for (int i = tid; i < NBK; i += 256) {
        int c = lh[i];
        lb[i] = c ? atomicAdd(&gcnt[i], c) : 0;
        lh[i] = 0;
    }
    __syncthreads();
    for (int e = base + tid; e < end; e += 256) {
        int d = dst[e];
        int b = d >> 7;
        int pos = lb[b] + atomicAdd(&lh[b], 1);
        if (pos < CAP) bkt[b * CAP + pos] = src[e] | ((d & (NPB - 1)) << 20);
    }
}

// ---------------- pass B: exclusive scan of the 782 bucket counts (1 block)
__global__ void scanB(const int* __restrict__ gcnt, int* __restrict__ gbase,
                      int* __restrict__ row) {
    __shared__ int s[256];
    int tid = threadIdx.x;
    int v[4];
    int sum = 0;
    for (int j = 0; j < 4; ++j) {
        int i = tid * 4 + j;
        v[j] = (i < NBK) ? min(gcnt[i], CAP) : 0;
        sum += v[j];
    }
    s[tid] = sum;
    for (int off = 1; off < 256; off <<= 1) {
        __syncthreads();
        int t = (tid >= off) ? s[tid - off] : 0;
        __syncthreads();
        s[tid] += t;
    }
    __syncthreads();
    int excl = s[tid] - sum;
    for (int j = 0; j < 4; ++j) {
        int i = tid * 4 + j;
        if (i < NBK) { gbase[i] = excl; excl += v[j]; }
    }
    if (tid == 0) row[Nn] = Ee;
}

// ---------------- pass C: per-bucket dense CSR placement + row + dis
__global__ void bucketC(const int* __restrict__ gcnt, const int* __restrict__ gbase,
                        const int* __restrict__ bkt, int* __restrict__ row,
                        float* __restrict__ dis, int* __restrict__ csr) {
    int b = blockIdx.x, tid = threadIdx.x;
    int cnt = min(gcnt[b], CAP);
    int base = gbase[b];
    __shared__ int sval[CAP];   // 8 KB
    __shared__ int ncnt[NPB];
    __shared__ int noff[NPB];
    __shared__ int ncur[NPB];
    if (tid < NPB) { ncnt[tid] = 0; ncur[tid] = 0; }
    __syncthreads();
    for (int i = tid; i < cnt; i += 256) {
        int v = bkt[b * CAP + i];
        sval[i] = v;
        atomicAdd(&ncnt[v >> 20], 1);
    }
    __syncthreads();
    if (tid < NPB) noff[tid] = ncnt[tid];
    __syncthreads();
    for (int off = 1; off < NPB; off <<= 1) {
        int t = (tid < NPB && tid >= off) ? noff[tid - off] : 0;
        __syncthreads();
        if (tid < NPB) noff[tid] += t;
        __syncthreads();
    }
    if (tid < NPB) {
        int excl = noff[tid] - ncnt[tid];   // inclusive -> exclusive
        noff[tid] = excl;
        int node = b * NPB + tid;
        if (node < Nn) {
            row[node] = base + excl;
            dis[node] = rsqrtf((float)ncnt[tid] + 1.0f);  // +1 = self-loop
        }
    }
    __syncthreads();
    for (int i = tid; i < cnt; i += 256) {
        int v = sval[i];
        int nl = v >> 20;
        int pos = base + noff[nl] + atomicAdd(&ncur[nl], 1);
        csr[pos] = v & 0xFFFFF;
    }
}

// ---------------- z(fp16) = (h @ W) * dis[n]; W column in registers, LDS repack
template <int K>
__global__ void mm_reg_h(const float* __restrict__ hin, const float* __restrict__ W,
                         const float* __restrict__ dis, __half* __restrict__ z) {
    int tid = threadIdx.x;
    int f = tid & 63, r = tid >> 6;  // 4 node rows per block-iter
    float wcol[K];
#pragma unroll
    for (int k = 0; k < K; ++k) wcol[k] = W[k * Hh + f];
    __shared__ float sh[4][K];
    __shared__ __align__(16) __half sout[4][64];   // 512 B
    for (int qd = blockIdx.x; qd * 4 < Nn; qd += gridDim.x) {
        int n0 = qd * 4;
        __syncthreads();
        for (int i = tid; i < 4 * K; i += 256) {
            int rr = i / K, c = i - rr * K;
            int n = n0 + rr;
            sh[rr][c] = (n < Nn) ? hin[(long)n * K + c] : 0.0f;
        }
        __syncthreads();
        int n = n0 + r;
        if (n < Nn) {
            float acc = 0.0f;
#pragma unroll
            for (int k = 0; k < K; ++k) acc += sh[r][k] * wcol[k];
            sout[r][f] = __float2half(acc * dis[n]);
        }
        __syncthreads();
        if (tid < 32) {  // 4 rows x 128 B, 16 B per lane
            int rr = tid >> 3, q = tid & 7;
            int n2 = n0 + rr;
            if (n2 < Nn)
                ((float4*)z)[(long)n2 * 8 + q] = ((const float4*)&sout[rr][0])[q];
        }
    }
}

// ---------------- fused agg(CSR, fp16 rows) + self-loop + BN + ReLU
// one wave per node; 8 edge-slots (sub) x 8 lanes (q) x 16 B (half8)
__global__ void agg_post_h(const __half* __restrict__ z, const float* __restrict__ dis,
                           const int* __restrict__ row, const int* __restrict__ csr,
                           const float* __restrict__ b, const float* __restrict__ g,
                           const float* __restrict__ be, const float* __restrict__ rm,
                           const float* __restrict__ rv, float* __restrict__ hout) {
    int n = (int)(((long)blockIdx.x * blockDim.x + threadIdx.x) >> 6);
    if (n >= Nn) return;
    int lane = threadIdx.x & 63, sub = lane >> 3, q = lane & 7;
    const float4* z4 = (const float4*)z;  // one float4 = 8 halves
    int e0 = row[n], e1 = row[n + 1];
    float2 ac[4];
    ac[0] = ac[1] = ac[2] = ac[3] = make_float2(0.f, 0.f);
    if (sub == 0) {  // self-loop term
        float4 raw = z4[(long)n * 8 + q];
        const __half2* hp = (const __half2*)&raw;
#pragma unroll
        for (int j = 0; j < 4; ++j) {
            float2 p = __half22float2(hp[j]);
            ac[j].x += p.x; ac[j].y += p.y;
        }
    }
    for (int e = e0 + sub; e < e1; e += 8) {
        int s = csr[e];
        float4 raw = z4[(long)s * 8 + q];
        const __half2* hp = (const __half2*)&raw;
#pragma unroll
        for (int j = 0; j < 4; ++j) {
            float2 p = __half22float2(hp[j]);
            ac[j].x += p.x; ac[j].y += p.y;
        }
    }
#pragma unroll
    for (int j = 0; j < 4; ++j) {
        ac[j].x += __shfl_xor(ac[j].x, 8);  ac[j].y += __shfl_xor(ac[j].y, 8);
        ac[j].x += __shfl_xor(ac[j].x, 16); ac[j].y += __shfl_xor(ac[j].y, 16);
        ac[j].x += __shfl_xor(ac[j].x, 32); ac[j].y += __shfl_xor(ac[j].y, 32);
    }
    if (sub == 0) {  // lane q owns features [8q, 8q+8)
        float dn = dis[n];
        float4 o[2];
        const float* af = (const float*)ac;
#pragma unroll
        for (int half_ = 0; half_ < 2; ++half_) {
            float4 bb  = ((const float4*)b)[q * 2 + half_];
            float4 gg  = ((const float4*)g)[q * 2 + half_];
            float4 rmm = ((const float4*)rm)[q * 2 + half_];
            float4 rvv = ((const float4*)rv)[q * 2 + half_];
            float4 bee = ((const float4*)be)[q * 2 + half_];
            const float* a4 = af + half_ * 4;
            o[half_].x = fmaxf((a4[0] * dn + bb.x - rmm.x) * (gg.x * rsqrtf(rvv.x + EPSF)) + bee.x, 0.f);
            o[half_].y = fmaxf((a4[1] * dn + bb.y - rmm.y) * (gg.y * rsqrtf(rvv.y + EPSF)) + bee.y, 0.f);
            o[half_].z = fmaxf((a4[2] * dn + bb.z - rmm.z) * (gg.z * rsqrtf(rvv.z + EPSF)) + bee.z, 0.f);
            o[half_].w = fmaxf((a4[3] * dn + bb.w - rmm.w) * (gg.w * rsqrtf(rvv.w + EPSF)) + bee.w, 0.f);
        }
        ((float4*)hout)[(long)n * 16 + q * 2]     = o[0];
        ((float4*)hout)[(long)n * 16 + q * 2 + 1] = o[1];
    }
}

// ---------------- fused mean-pool + both heads (one block per graph)
__device__ __forceinline__ int lower_bound_i(const int* __restrict__ a, int n, int v) {
    int lo = 0, hi = n;
    while (lo < hi) {
        int m = (lo + hi) >> 1;
        if (a[m] < v) lo = m + 1; else hi = m;
    }
    return lo;
}

__global__ void pool_heads(const float* __restrict__ h, const int* __restrict__ batch,
                           const float* __restrict__ sw1, const float* __restrict__ sb1,
                           const float* __restrict__ sw2, const float* __restrict__ sb2,
                           const float* __restrict__ aw1, const float* __restrict__ ab1,
                           const float* __restrict__ aw2, const float* __restrict__ ab2,
                           float* __restrict__ out) {
    int gph = blockIdx.x, tid = threadIdx.x;
    __shared__ int slo, shi;
    __shared__ float4 r4[256];
    __shared__ float semb[64];
    __shared__ float s1[32], sa[32];
    if (tid == 0) {
        slo = lower_bound_i(batch, Nn, gph);
        shi = lower_bound_i(batch, Nn, gph + 1);
    }
    __syncthreads();
    int lo = slo, hi = shi;
    int q = tid & 15, sub = tid >> 4;  // 16 node rows in flight
    const float4* h4 = (const float4*)h;
    float4 acc = make_float4(0.f, 0.f, 0.f, 0.f);
    for (int n = lo + sub; n < hi; n += 16) {
        float4 v = h4[(long)n * 16 + q];
        acc.x += v.x; acc.y += v.y; acc.z += v.z; acc.w += v.w;
    }
    r4[tid] = acc;
    __syncthreads();
    if (tid < 64) {
        const float* rf = (const float*)r4;
        float s = 0.f;
        for (int sb_ = 0; sb_ < 16; ++sb_) s += rf[sb_ * 64 + tid];
        semb[tid] = s / fmaxf((float)(hi - lo), 1.0f);
    }
    __syncthreads();
    if (tid < 32) {
        float a1 = sb1[tid], a2 = ab1[tid];
        for (int k = 0; k < 64; ++k) {
            float e = semb[k];
            a1 += e * sw1[k * 32 + tid];
            a2 += e * aw1[k * 32 + tid];
        }
        s1[tid] = fmaxf(a1, 0.0f);
        sa[tid] = fmaxf(a2, 0.0f);
    }
    __syncthreads();
    if (tid == 0) {
        float acc2 = sb2[0];
        for (int k = 0; k < 32; ++k) acc2 += s1[k] * sw2[k];
        out[gph] = 1.0f / (1.0f + expf(-acc2));
    }
    if (tid >= 4 && tid < 8) {
        int t = tid - 4;
        float acc2 = ab2[t];
        for (int k = 0; k < 32; ++k) acc2 += sa[k] * aw2[k * 4 + t];
        out[Gg + gph * 4 + t] = acc2;
    }
}

extern "C" void kernel_launch(void* const* d_in, const int* in_sizes, int n_in,
                              void* d_out, int out_size, void* d_ws, size_t ws_size,
                              hipStream_t stream) {
    const float* x   = (const float*)d_in[0];
    const int*   ei  = (const int*)d_in[1];
    const int* batch = (const int*)d_in[2];
    const float* W1 = (const float*)d_in[4];
    const float* b1 = (const float*)d_in[5];
    const float* W2 = (const float*)d_in[6];
    const float* b2 = (const float*)d_in[7];
    const float* W3 = (const float*)d_in[8];
    const float* b3 = (const float*)d_in[9];
    const float* g1  = (const float*)d_in[10];
    const float* be1 = (const float*)d_in[11];
    const float* rm1 = (const float*)d_in[12];
    const float* rv1 = (const float*)d_in[13];
    const float* g2  = (const float*)d_in[14];
    const float* be2 = (const float*)d_in[15];
    const float* rm2 = (const float*)d_in[16];
    const float* rv2 = (const float*)d_in[17];
    const float* g3  = (const float*)d_in[18];
    const float* be3 = (const float*)d_in[19];
    const float* rm3 = (const float*)d_in[20];
    const float* rv3 = (const float*)d_in[21];
    const float* sw1 = (const float*)d_in[22];
    const float* sb1 = (const float*)d_in[23];
    const float* sw2 = (const float*)d_in[24];
    const float* sb2 = (const float*)d_in[25];
    const float* aw1 = (const float*)d_in[26];
    const float* ab1 = (const float*)d_in[27];
    const float* aw2 = (const float*)d_in[28];
    const float* ab2 = (const float*)d_in[29];
    float* out = (float*)d_out;

    // ---- workspace carve-up (256B-aligned chunks)
    char* ws = (char*)d_ws;
    auto align256 = [](size_t v) { return (v + 255) & ~(size_t)255; };
    size_t off = 0;
    auto take = [&](size_t bytes) { char* p = ws + off; off += align256(bytes); return p; };
    int*    gcnt  = (int*)   take((size_t)NBK * 4);
    int*    gbase = (int*)   take((size_t)NBK * 4);
    float*  dis   = (float*) take((size_t)Nn * 4);
    int*    row   = (int*)   take((size_t)(Nn + 1) * 4);
    int*    bkt   = (int*)   take((size_t)NBK * CAP * 4);   // 6.4 MB
    int*    csr   = (int*)   take((size_t)Ee * 4);          // 4.8 MB
    __half* z     = (__half*)take((size_t)Nn * Hh * 2);     // 12.8 MB (fp16)
    float*  h     = (float*) take((size_t)Nn * Hh * 4);     // 25.6 MB

    const int* srcp = ei;        // edge_index[0]
    const int* dstp = ei + Ee;   // edge_index[1]

    const int nWGA      = (Ee + CH - 1) / CH;       // 586
    const int aggBlocks = (Nn + 3) / 4;             // 1 wave per node, 4/block
    const int mmBlocks  = 2048;                     // grid-stride

    // ---- CSR build (bucketed; no cross-XCD false sharing)
    hipMemsetAsync(gcnt, 0, (size_t)NBK * 4, stream);
    bucketA<<<nWGA, 256, 0, stream>>>(srcp, dstp, gcnt, bkt);
    scanB<<<1, 256, 0, stream>>>(gcnt, gbase, row);
    bucketC<<<NBK, 256, 0, stream>>>(gcnt, gbase, bkt, row, dis, csr);

    // ---- layer 1 (K = D = 20)
    mm_reg_h<Dd><<<mmBlocks, 256, 0, stream>>>(x, W1, dis, z);
    agg_post_h<<<aggBlocks, 256, 0, stream>>>(z, dis, row, csr, b1, g1, be1, rm1, rv1, h);

    // ---- layer 2 (K = H = 64)
    mm_reg_h<Hh><<<mmBlocks, 256, 0, stream>>>(h, W2, dis, z);
    agg_post_h<<<aggBlocks, 256, 0, stream>>>(z, dis, row, csr, b2, g2, be2, rm2, rv2, h);

    // ---- layer 3
    mm_reg_h<Hh><<<mmBlocks, 256, 0, stream>>>(h, W3, dis, z);
    agg_post_h<<<aggBlocks, 256, 0, stream>>>(z, dis, row, csr, b3, g3, be3, rm3, rv3, h);

    // ---- fused pooling + heads
    pool_heads<<<Gg, 256, 0, stream>>>(h, batch, sw1, sb1, sw2, sb2,
                                       aw1, ab1, aw2, ab2, out);
}